// Round 3
// baseline (226.343 us; speedup 1.0000x reference)
//
#include <hip/hip_runtime.h>
#include <hip/hip_bf16.h>

#define BB 8
#define NN 256
#define DD 128
#define HH 512
#define LL 2
#define EPSV 1e-5f
#define TPB 8   // tokens per block in k_layer

__device__ __forceinline__ void waveRed2(float &a, float &b){
  #pragma unroll
  for (int off=32; off>=1; off>>=1){
    a += __shfl_xor(a, off, 64);
    b += __shfl_xor(b, off, 64);
  }
}

// ---------------- embed + LN: one block (128 thr) per token ----------------
__global__ __launch_bounds__(128) void k_embed(
    const float* __restrict__ x, const float* __restrict__ We,
    const float* __restrict__ be, const float* __restrict__ ge,
    const float* __restrict__ bge, float* __restrict__ h)
{
  int t = blockIdx.x;
  int d = threadIdx.x;
  float x0 = x[t*2], x1 = x[t*2+1];
  float v = fmaf(x0, We[d], fmaf(x1, We[DD + d], be[d]));
  __shared__ float red[2][2];
  float s = v, q = v*v;
  waveRed2(s,q);
  int wid = d >> 6, lane = d & 63;
  if (lane == 0){ red[wid][0]=s; red[wid][1]=q; }
  __syncthreads();
  float S = red[0][0]+red[1][0], Q = red[0][1]+red[1][1];
  float m = S * (1.0f/DD);
  float var = Q*(1.0f/DD) - m*m;
  float rs = rsqrtf(var + EPSV);
  h[t*DD + d] = (v - m)*rs*ge[d] + bge[d];
}

// ------------- pool stats: max1/max2/argmax over n per (b,d) -------------
// block = 512 threads: (d = tid&127, part = tid>>7 scans 64 n's), grid = B
__global__ __launch_bounds__(512) void k_pool(
    const float* __restrict__ h,
    float* __restrict__ pm1, float* __restrict__ pm2, int* __restrict__ parg)
{
  int b = blockIdx.x;
  int d = threadIdx.x & 127;
  int part = threadIdx.x >> 7;
  float m1 = -3.4e38f, m2 = -3.4e38f; int am = 0;
  const float* hb = h + (size_t)b*NN*DD;
  int n0 = part*64;
  #pragma unroll 8
  for (int n = n0; n < n0+64; ++n){
    float v = hb[n*DD + d];
    if (v > m1){ m2 = m1; m1 = v; am = n; }
    else if (v > m2){ m2 = v; }
  }
  __shared__ float sm1[4][DD], sm2[4][DD];
  __shared__ int sam[4][DD];
  sm1[part][d]=m1; sm2[part][d]=m2; sam[part][d]=am;
  __syncthreads();
  if (part==0){
    #pragma unroll
    for (int p=1;p<4;++p){
      float o1=sm1[p][d], o2=sm2[p][d]; int oa=sam[p][d];
      if (o1 > m1){ m2 = fmaxf(o2, m1); m1 = o1; am = oa; }
      else        { m2 = fmaxf(m2, o1); }
    }
    pm1[b*DD+d]=m1; pm2[b*DD+d]=m2; parg[b*DD+d]=am;
  }
}

// ----- fused: pooled-concat linear + res + LN, FF(relu) + res + LN -----
// 128 threads (thread = output dim d), TPB tokens per block, weights
// pre-offset to layer i by the host. h is updated in place (h == d_out).
__global__ __launch_bounds__(128) void k_layer(
    float* __restrict__ h,
    const float* __restrict__ pm1, const float* __restrict__ pm2,
    const int* __restrict__ parg,
    const float* __restrict__ Wp, const float* __restrict__ bp,
    const float* __restrict__ gp, const float* __restrict__ bgp,
    const float* __restrict__ W1, const float* __restrict__ b1,
    const float* __restrict__ W2, const float* __restrict__ b2,
    const float* __restrict__ gf, const float* __restrict__ bgf)
{
  int d = threadIdx.x;
  int t0 = blockIdx.x * TPB;
  int wid = d >> 6, lane = d & 63;

  __shared__ float cat[TPB][2*DD];   // 8 KB
  __shared__ float h1s[TPB][DD];     // 4 KB
  __shared__ float us[TPB][HH];      // 16 KB
  __shared__ float red[TPB][2][2];

  // ---- load own h + pooled into cat ----
  #pragma unroll
  for (int t=0;t<TPB;++t){
    int tok = t0+t; int b = tok >> 8; int n = tok & 255;
    float hv = h[(size_t)tok*DD + d];
    cat[t][d] = hv;
    int am = parg[b*DD+d];
    cat[t][DD+d] = (n==am) ? pm2[b*DD+d] : pm1[b*DD+d];
  }
  __syncthreads();

  // ---- stage A: y = cat @ Wp + bp ----
  float y[TPB];
  {
    float bpv = bp[d];
    #pragma unroll
    for (int t=0;t<TPB;++t) y[t] = bpv;
  }
  for (int k=0;k<2*DD;k+=4){
    float w0=Wp[(k  )*DD+d];
    float w1=Wp[(k+1)*DD+d];
    float w2=Wp[(k+2)*DD+d];
    float w3=Wp[(k+3)*DD+d];
    #pragma unroll
    for (int t=0;t<TPB;++t){
      float4 c = *(const float4*)&cat[t][k];
      y[t]=fmaf(c.x,w0,y[t]); y[t]=fmaf(c.y,w1,y[t]);
      y[t]=fmaf(c.z,w2,y[t]); y[t]=fmaf(c.w,w3,y[t]);
    }
  }

  // ---- residual + LN -> h1 ----
  {
    float gpv=gp[d], bgpv=bgp[d];
    #pragma unroll
    for (int t=0;t<TPB;++t){
      float v = y[t] + cat[t][d];
      y[t] = v;
      float s=v,q=v*v; waveRed2(s,q);
      if (lane==0){ red[t][wid][0]=s; red[t][wid][1]=q; }
    }
    __syncthreads();
    #pragma unroll
    for (int t=0;t<TPB;++t){
      float S=red[t][0][0]+red[t][1][0], Q=red[t][0][1]+red[t][1][1];
      float m=S*(1.f/DD), var=Q*(1.f/DD)-m*m, rs=rsqrtf(var+EPSV);
      h1s[t][d] = (y[t]-m)*rs*gpv + bgpv;
    }
  }
  __syncthreads();

  // ---- stage B: u = relu(h1 @ W1 + b1), each thread 4 j's ----
  float acc[TPB][4];
  #pragma unroll
  for (int t=0;t<TPB;++t){
    acc[t][0]=b1[d]; acc[t][1]=b1[128+d];
    acc[t][2]=b1[256+d]; acc[t][3]=b1[384+d];
  }
  for (int kd=0; kd<DD; kd+=4){
    float w[4][4];
    #pragma unroll
    for (int u=0;u<4;++u){
      const float* r = W1 + (size_t)(kd+u)*HH;
      w[u][0]=r[d]; w[u][1]=r[128+d];
      w[u][2]=r[256+d]; w[u][3]=r[384+d];
    }
    #pragma unroll
    for (int t=0;t<TPB;++t){
      float4 hv = *(const float4*)&h1s[t][kd];
      #pragma unroll
      for (int j=0;j<4;++j){
        acc[t][j]=fmaf(hv.x,w[0][j],acc[t][j]);
        acc[t][j]=fmaf(hv.y,w[1][j],acc[t][j]);
        acc[t][j]=fmaf(hv.z,w[2][j],acc[t][j]);
        acc[t][j]=fmaf(hv.w,w[3][j],acc[t][j]);
      }
    }
  }
  #pragma unroll
  for (int t=0;t<TPB;++t){
    us[t][d]     = fmaxf(acc[t][0],0.f);
    us[t][128+d] = fmaxf(acc[t][1],0.f);
    us[t][256+d] = fmaxf(acc[t][2],0.f);
    us[t][384+d] = fmaxf(acc[t][3],0.f);
  }
  __syncthreads();

  // ---- stage C: z = u @ W2 + b2 ----
  float z[TPB];
  {
    float b2v = b2[d];
    #pragma unroll
    for (int t=0;t<TPB;++t) z[t]=b2v;
  }
  for (int j=0;j<HH;j+=4){
    float w0=W2[(j  )*DD+d];
    float w1=W2[(j+1)*DD+d];
    float w2=W2[(j+2)*DD+d];
    float w3=W2[(j+3)*DD+d];
    #pragma unroll
    for (int t=0;t<TPB;++t){
      float4 u4 = *(const float4*)&us[t][j];
      z[t]=fmaf(u4.x,w0,z[t]); z[t]=fmaf(u4.y,w1,z[t]);
      z[t]=fmaf(u4.z,w2,z[t]); z[t]=fmaf(u4.w,w3,z[t]);
    }
  }

  // ---- residual + LN -> h (in place; h == d_out) ----
  {
    float gfv=gf[d], bgfv=bgf[d];
    #pragma unroll
    for (int t=0;t<TPB;++t){
      float v = z[t] + h1s[t][d];
      z[t]=v;
      float s=v,q=v*v; waveRed2(s,q);
      if (lane==0){ red[t][wid][0]=s; red[t][wid][1]=q; }
    }
    __syncthreads();
    #pragma unroll
    for (int t=0;t<TPB;++t){
      float S=red[t][0][0]+red[t][1][0], Q=red[t][0][1]+red[t][1][1];
      float m=S*(1.f/DD), var=Q*(1.f/DD)-m*m, rs=rsqrtf(var+EPSV);
      float hv=(z[t]-m)*rs*gfv+bgfv;
      int tok=t0+t;
      h[(size_t)tok*DD+d]=hv;
    }
  }
}

extern "C" void kernel_launch(void* const* d_in, const int* in_sizes, int n_in,
                              void* d_out, int out_size, void* d_ws, size_t ws_size,
                              hipStream_t stream)
{
  const float* x   = (const float*)d_in[0];
  const float* We  = (const float*)d_in[1];
  const float* be  = (const float*)d_in[2];
  const float* ge  = (const float*)d_in[3];
  const float* bge = (const float*)d_in[4];
  const float* Wp  = (const float*)d_in[5];
  const float* bp  = (const float*)d_in[6];
  const float* gp  = (const float*)d_in[7];
  const float* bgp = (const float*)d_in[8];
  const float* W1  = (const float*)d_in[9];
  const float* b1  = (const float*)d_in[10];
  const float* W2  = (const float*)d_in[11];
  const float* b2  = (const float*)d_in[12];
  const float* gf  = (const float*)d_in[13];
  const float* bgf = (const float*)d_in[14];

  // h lives in d_out (exactly B*N*D floats); final layer's in-place update
  // IS the output. ws only holds the pool stats.
  float* h    = (float*)d_out;
  float* pm1  = (float*)d_ws;
  float* pm2  = pm1 + BB*DD;
  int*   parg = (int*)(pm2 + BB*DD);

  k_embed<<<BB*NN, 128, 0, stream>>>(x, We, be, ge, bge, h);
  for (int i=0;i<LL;++i){
    k_pool<<<BB, 512, 0, stream>>>(h, pm1, pm2, parg);
    k_layer<<<(BB*NN)/TPB, 128, 0, stream>>>(h, pm1, pm2, parg,
        Wp + (size_t)i*2*DD*DD, bp + i*DD, gp + i*DD, bgp + i*DD,
        W1 + (size_t)i*DD*HH, b1 + i*HH, W2 + (size_t)i*HH*DD, b2 + i*DD,
        gf + i*DD, bgf + i*DD);
  }
}

// Round 4
// 151.418 us; speedup vs baseline: 1.4948x; 1.4948x over previous
//
#include <hip/hip_runtime.h>
#include <hip/hip_bf16.h>

#define BB 8
#define NN 256
#define DD 128
#define HH 512
#define LL 2
#define EPSV 1e-5f
#define TPB 8   // tokens per block in k_layer

__device__ __forceinline__ void waveRed2(float &a, float &b){
  #pragma unroll
  for (int off=32; off>=1; off>>=1){
    a += __shfl_xor(a, off, 64);
    b += __shfl_xor(b, off, 64);
  }
}

// ---------------- embed + LN: one block (128 thr) per token ----------------
__global__ __launch_bounds__(128) void k_embed(
    const float* __restrict__ x, const float* __restrict__ We,
    const float* __restrict__ be, const float* __restrict__ ge,
    const float* __restrict__ bge, float* __restrict__ h)
{
  int t = blockIdx.x;
  int d = threadIdx.x;
  float x0 = x[t*2], x1 = x[t*2+1];
  float v = fmaf(x0, We[d], fmaf(x1, We[DD + d], be[d]));
  __shared__ float red[2][2];
  float s = v, q = v*v;
  waveRed2(s,q);
  int wid = d >> 6, lane = d & 63;
  if (lane == 0){ red[wid][0]=s; red[wid][1]=q; }
  __syncthreads();
  float S = red[0][0]+red[1][0], Q = red[0][1]+red[1][1];
  float m = S * (1.0f/DD);
  float var = Q*(1.0f/DD) - m*m;
  float rs = rsqrtf(var + EPSV);
  h[t*DD + d] = (v - m)*rs*ge[d] + bge[d];
}

// ------------- pool stats: max1/max2/argmax over n per (b,d) -------------
// block = 1024 threads: (d = tid&127, part = tid>>7 scans 32 n's), grid = B
__global__ __launch_bounds__(1024) void k_pool(
    const float* __restrict__ h,
    float* __restrict__ pm1, float* __restrict__ pm2, int* __restrict__ parg)
{
  int b = blockIdx.x;
  int d = threadIdx.x & 127;
  int part = threadIdx.x >> 7;           // 0..7
  float m1 = -3.4e38f, m2 = -3.4e38f; int am = 0;
  const float* hb = h + (size_t)b*NN*DD;
  int n0 = part*32;
  #pragma unroll 8
  for (int n = n0; n < n0+32; ++n){
    float v = hb[n*DD + d];
    if (v > m1){ m2 = m1; m1 = v; am = n; }
    else if (v > m2){ m2 = v; }
  }
  __shared__ float sm1[8][DD], sm2[8][DD];
  __shared__ int sam[8][DD];
  sm1[part][d]=m1; sm2[part][d]=m2; sam[part][d]=am;
  __syncthreads();
  if (part==0){
    #pragma unroll
    for (int p=1;p<8;++p){
      float o1=sm1[p][d], o2=sm2[p][d]; int oa=sam[p][d];
      if (o1 > m1){ m2 = fmaxf(o2, m1); m1 = o1; am = oa; }
      else        { m2 = fmaxf(m2, o1); }
    }
    pm1[b*DD+d]=m1; pm2[b*DD+d]=m2; parg[b*DD+d]=am;
  }
}

// ----- fused layer, split-K: 512 threads = (d 0..127) x (part 0..3) -----
// Each part covers a quarter of the contraction dim in stages A and C; the
// 4 partials meet in LDS. Stage B uses all 512 threads as distinct j-columns.
// Per-thread global loads: 64(A) + 128(B) + 128(C) vs 1280 in the 128-thread
// version; waves/CU: 8 vs 2. h is updated in place (h == d_out).
__global__ __launch_bounds__(512) void k_layer(
    float* __restrict__ h,
    const float* __restrict__ pm1, const float* __restrict__ pm2,
    const int* __restrict__ parg,
    const float* __restrict__ Wp, const float* __restrict__ bp,
    const float* __restrict__ gp, const float* __restrict__ bgp,
    const float* __restrict__ W1, const float* __restrict__ b1,
    const float* __restrict__ W2, const float* __restrict__ b2,
    const float* __restrict__ gf, const float* __restrict__ bgf)
{
  int tid = threadIdx.x;
  int d    = tid & 127;
  int part = tid >> 7;          // 0..3
  int lane = tid & 63;
  int wid  = (tid >> 6) & 1;    // wave within a 128-thread d-group
  int t0 = blockIdx.x * TPB;

  __shared__ float cat[TPB][2*DD];   // 8 KB
  __shared__ float h1s[TPB][DD];     // 4 KB
  __shared__ float us[TPB][HH];      // 16 KB
  __shared__ float pA[4][TPB][DD];   // 16 KB (reused by stage C)
  __shared__ float red[TPB][2][2];

  // ---- load cat: 2048 entries, 4 per thread (wave-uniform branch) ----
  {
    int c = tid & 255, g = tid >> 8;   // waves 0-3: c<128 ; waves 4-7: c>=128
    #pragma unroll
    for (int tt=0; tt<4; ++tt){
      int t = g*4 + tt; int tok = t0 + t; int b = tok >> 8; int n = tok & 255;
      float v;
      if (c < DD){
        v = h[(size_t)tok*DD + c];
      } else {
        int cc = c - DD;
        int am = parg[b*DD + cc];
        v = (n == am) ? pm2[b*DD + cc] : pm1[b*DD + cc];
      }
      cat[t][c] = v;
    }
  }
  __syncthreads();

  // ---- stage A: partial y = cat[:, part*64 : part*64+64] @ Wp ----
  float y[TPB];
  #pragma unroll
  for (int t=0;t<TPB;++t) y[t] = 0.f;
  {
    const float* wp = Wp + d;
    for (int k = part*64; k < part*64 + 64; k += 4){
      float w0 = wp[(k+0)*DD];
      float w1 = wp[(k+1)*DD];
      float w2 = wp[(k+2)*DD];
      float w3 = wp[(k+3)*DD];
      #pragma unroll
      for (int t=0;t<TPB;++t){
        float4 c4 = *(const float4*)&cat[t][k];
        y[t]=fmaf(c4.x,w0,y[t]); y[t]=fmaf(c4.y,w1,y[t]);
        y[t]=fmaf(c4.z,w2,y[t]); y[t]=fmaf(c4.w,w3,y[t]);
      }
    }
  }
  #pragma unroll
  for (int t=0;t<TPB;++t) pA[part][t][d] = y[t];
  __syncthreads();

  // ---- combine partials + bias + residual, LN -> h1s (2 tokens/part) ----
  {
    float vA[2];
    #pragma unroll
    for (int tt=0;tt<2;++tt){
      int t = part*2 + tt;
      float v = pA[0][t][d] + pA[1][t][d] + pA[2][t][d] + pA[3][t][d]
              + bp[d] + cat[t][d];
      vA[tt] = v;
      float s=v, q=v*v; waveRed2(s,q);
      if (lane==0){ red[t][wid][0]=s; red[t][wid][1]=q; }
    }
    __syncthreads();
    float gpv = gp[d], bgpv = bgp[d];
    #pragma unroll
    for (int tt=0;tt<2;++tt){
      int t = part*2 + tt;
      float S=red[t][0][0]+red[t][1][0], Q=red[t][0][1]+red[t][1][1];
      float m=S*(1.f/DD), var=Q*(1.f/DD)-m*m, rs=rsqrtf(var+EPSV);
      h1s[t][d] = (vA[tt]-m)*rs*gpv + bgpv;
    }
  }
  __syncthreads();

  // ---- stage B: u = relu(h1 @ W1 + b1); thread = column j ----
  {
    int j = tid;
    float acc[TPB];
    float b1v = b1[j];
    #pragma unroll
    for (int t=0;t<TPB;++t) acc[t]=b1v;
    const float* w1p = W1 + j;
    for (int k=0;k<DD;k+=4){
      float w0 = w1p[(k+0)*HH];
      float w1 = w1p[(k+1)*HH];
      float w2 = w1p[(k+2)*HH];
      float w3 = w1p[(k+3)*HH];
      #pragma unroll
      for (int t=0;t<TPB;++t){
        float4 h4 = *(const float4*)&h1s[t][k];
        acc[t]=fmaf(h4.x,w0,acc[t]); acc[t]=fmaf(h4.y,w1,acc[t]);
        acc[t]=fmaf(h4.z,w2,acc[t]); acc[t]=fmaf(h4.w,w3,acc[t]);
      }
    }
    #pragma unroll
    for (int t=0;t<TPB;++t) us[t][j] = fmaxf(acc[t], 0.f);
  }
  __syncthreads();

  // ---- stage C: partial z = u[:, part*128 : part*128+128] @ W2 ----
  float z[TPB];
  #pragma unroll
  for (int t=0;t<TPB;++t) z[t]=0.f;
  {
    const float* w2p = W2 + d;
    for (int j = part*128; j < part*128 + 128; j += 4){
      float w0 = w2p[(j+0)*DD];
      float w1 = w2p[(j+1)*DD];
      float w2 = w2p[(j+2)*DD];
      float w3 = w2p[(j+3)*DD];
      #pragma unroll
      for (int t=0;t<TPB;++t){
        float4 u4 = *(const float4*)&us[t][j];
        z[t]=fmaf(u4.x,w0,z[t]); z[t]=fmaf(u4.y,w1,z[t]);
        z[t]=fmaf(u4.z,w2,z[t]); z[t]=fmaf(u4.w,w3,z[t]);
      }
    }
  }
  __syncthreads();   // us no longer needed; pA reuse below
  #pragma unroll
  for (int t=0;t<TPB;++t) pA[part][t][d] = z[t];
  __syncthreads();

  // ---- combine partials + bias + residual, LN -> h (in place) ----
  {
    float vC[2];
    #pragma unroll
    for (int tt=0;tt<2;++tt){
      int t = part*2 + tt;
      float v = pA[0][t][d] + pA[1][t][d] + pA[2][t][d] + pA[3][t][d]
              + b2[d] + h1s[t][d];
      vC[tt] = v;
      float s=v, q=v*v; waveRed2(s,q);
      if (lane==0){ red[t][wid][0]=s; red[t][wid][1]=q; }
    }
    __syncthreads();
    float gfv = gf[d], bgfv = bgf[d];
    #pragma unroll
    for (int tt=0;tt<2;++tt){
      int t = part*2 + tt;
      float S=red[t][0][0]+red[t][1][0], Q=red[t][0][1]+red[t][1][1];
      float m=S*(1.f/DD), var=Q*(1.f/DD)-m*m, rs=rsqrtf(var+EPSV);
      h[(size_t)(t0+t)*DD + d] = (vC[tt]-m)*rs*gfv + bgfv;
    }
  }
}

extern "C" void kernel_launch(void* const* d_in, const int* in_sizes, int n_in,
                              void* d_out, int out_size, void* d_ws, size_t ws_size,
                              hipStream_t stream)
{
  const float* x   = (const float*)d_in[0];
  const float* We  = (const float*)d_in[1];
  const float* be  = (const float*)d_in[2];
  const float* ge  = (const float*)d_in[3];
  const float* bge = (const float*)d_in[4];
  const float* Wp  = (const float*)d_in[5];
  const float* bp  = (const float*)d_in[6];
  const float* gp  = (const float*)d_in[7];
  const float* bgp = (const float*)d_in[8];
  const float* W1  = (const float*)d_in[9];
  const float* b1  = (const float*)d_in[10];
  const float* W2  = (const float*)d_in[11];
  const float* b2  = (const float*)d_in[12];
  const float* gf  = (const float*)d_in[13];
  const float* bgf = (const float*)d_in[14];

  // h lives in d_out (exactly B*N*D floats); final layer's in-place update
  // IS the output. ws only holds the pool stats.
  float* h    = (float*)d_out;
  float* pm1  = (float*)d_ws;
  float* pm2  = pm1 + BB*DD;
  int*   parg = (int*)(pm2 + BB*DD);

  k_embed<<<BB*NN, 128, 0, stream>>>(x, We, be, ge, bge, h);
  for (int i=0;i<LL;++i){
    k_pool<<<BB, 1024, 0, stream>>>(h, pm1, pm2, parg);
    k_layer<<<(BB*NN)/TPB, 512, 0, stream>>>(h, pm1, pm2, parg,
        Wp + (size_t)i*2*DD*DD, bp + i*DD, gp + i*DD, bgp + i*DD,
        W1 + (size_t)i*DD*HH, b1 + i*HH, W2 + (size_t)i*HH*DD, b2 + i*DD,
        gf + i*DD, bgf + i*DD);
  }
}

// Round 5
// 128.475 us; speedup vs baseline: 1.7618x; 1.1786x over previous
//
#include <hip/hip_runtime.h>

#define BB 8
#define NN 256
#define DD 128
#define HH 512
#define LL 2
#define EPSV 1e-5f
#define TPB 4            // tokens per block
#define BPB (NN/TPB)     // blocks (= pool partials) per batch = 64

__device__ __forceinline__ void waveRed2(float &a, float &b){
  #pragma unroll
  for (int off=32; off>=1; off>>=1){
    a += __shfl_xor(a, off, 64);
    b += __shfl_xor(b, off, 64);
  }
}

// merge candidate set (o1,o2,oa) into running (m1,m2,am)
__device__ __forceinline__ void poolMerge(float &m1, float &m2, int &am,
                                          float o1, float o2, int oa){
  if (o1 > m1){ m2 = fmaxf(m1, o2); m1 = o1; am = oa; }
  else        { m2 = fmaxf(m2, o1); }
}

// ---- embed + LN + pool-partial: 512 thr = (token 0..3) x (d 0..127) ----
__global__ __launch_bounds__(512) void k_embed(
    const float* __restrict__ x, const float* __restrict__ We,
    const float* __restrict__ be, const float* __restrict__ ge,
    const float* __restrict__ bge, float* __restrict__ h,
    float* __restrict__ pm1p, float* __restrict__ pm2p, int* __restrict__ pargp)
{
  int tid = threadIdx.x;
  int t = tid >> 7, d = tid & 127;
  int lane = tid & 63, wid = (tid >> 6) & 1;
  int t0 = blockIdx.x * TPB;
  int tok = t0 + t;
  __shared__ float red[TPB][2][2];
  __shared__ float hf[TPB][DD];
  float x0 = x[tok*2], x1 = x[tok*2+1];
  float v = fmaf(x0, We[d], fmaf(x1, We[DD+d], be[d]));
  float s=v, q=v*v; waveRed2(s,q);
  if (lane==0){ red[t][wid][0]=s; red[t][wid][1]=q; }
  __syncthreads();
  float S=red[t][0][0]+red[t][1][0], Q=red[t][0][1]+red[t][1][1];
  float m=S*(1.f/DD), var=Q*(1.f/DD)-m*m, rs=rsqrtf(var+EPSV);
  float hv = (v-m)*rs*ge[d] + bge[d];
  h[(size_t)tok*DD + d] = hv;
  hf[t][d] = hv;
  __syncthreads();
  if (t==0){
    int b = t0 >> 8;
    int n0 = t0 & 255;
    float m1 = hf[0][d], m2 = -3.4e38f; int am = n0;
    #pragma unroll
    for (int p=1;p<TPB;++p) poolMerge(m1,m2,am, hf[p][d], -3.4e38f, n0+p);
    int blk = (t0 >> 2) & (BPB-1);
    size_t idx = ((size_t)b*BPB + blk)*DD + d;
    pm1p[idx]=m1; pm2p[idx]=m2; pargp[idx]=am;
  }
}

// ---- fused layer: merge pool partials, concat-linear+LN, FF+LN, emit
//      next-layer pool partials. 512 thr = (d 0..127) x (part 0..3),
//      TPB=4 tokens/block, grid 512 (2 blocks/CU). h in place (h==d_out).
__global__ __launch_bounds__(512) void k_layer(
    float* __restrict__ h,
    const float* __restrict__ pm1p, const float* __restrict__ pm2p,
    const int* __restrict__ pargp,
    float* __restrict__ qm1p, float* __restrict__ qm2p, int* __restrict__ qargp,
    int write_pool,
    const float* __restrict__ Wp, const float* __restrict__ bp,
    const float* __restrict__ gp, const float* __restrict__ bgp,
    const float* __restrict__ W1, const float* __restrict__ b1,
    const float* __restrict__ W2, const float* __restrict__ b2,
    const float* __restrict__ gf, const float* __restrict__ bgf)
{
  int tid = threadIdx.x;
  int d = tid & 127, part = tid >> 7;
  int lane = tid & 63, wid = (tid >> 6) & 1;
  int t0 = blockIdx.x * TPB;
  int b = t0 >> 8;

  __shared__ float cat[TPB][2*DD];       // 4 KB (reused as final-h buffer)
  __shared__ float h1s[TPB][DD];         // 2 KB
  __shared__ float us[TPB][HH];          // 8 KB
  __shared__ float pA[4][TPB][DD];       // 8 KB
  __shared__ float red[TPB][2][2];
  __shared__ float fm1[DD], fm2[DD];
  __shared__ int   fam[DD];
  __shared__ float sm1[4][DD], sm2[4][DD];
  __shared__ int   sam[4][DD];

  // ---- merge the batch's 64 pool partials (16 per part) ----
  {
    size_t base = ((size_t)b*BPB + part*16)*DD + d;
    float m1 = pm1p[base], m2 = pm2p[base]; int am = pargp[base];
    #pragma unroll
    for (int i=1;i<16;++i)
      poolMerge(m1,m2,am, pm1p[base+(size_t)i*DD], pm2p[base+(size_t)i*DD],
                pargp[base+(size_t)i*DD]);
    sm1[part][d]=m1; sm2[part][d]=m2; sam[part][d]=am;
  }
  __syncthreads();
  if (part==0){
    float m1=sm1[0][d], m2=sm2[0][d]; int am=sam[0][d];
    #pragma unroll
    for (int p=1;p<4;++p) poolMerge(m1,m2,am, sm1[p][d], sm2[p][d], sam[p][d]);
    fm1[d]=m1; fm2[d]=m2; fam[d]=am;
  }
  __syncthreads();

  // ---- build cat[4][256]: 2 entries per thread, wave-uniform branch ----
  #pragma unroll
  for (int rep=0; rep<2; ++rep){
    int e = rep*512 + tid;
    int t = e >> 8, c = e & 255;
    int tok = t0 + t, n = (t0 & 255) + t;
    float v;
    if (c < DD) v = h[(size_t)tok*DD + c];
    else { int cc = c - DD; v = (n==fam[cc]) ? fm2[cc] : fm1[cc]; }
    cat[t][c] = v;
  }
  __syncthreads();

  // ---- stage A: partial y over k in [part*64, part*64+64) ----
  float y[TPB];
  #pragma unroll
  for (int t=0;t<TPB;++t) y[t]=0.f;
  {
    const float* wp = Wp + d;
    int k0 = part*64;
    for (int k=k0; k<k0+64; k+=4){
      float w0=wp[(k+0)*DD], w1=wp[(k+1)*DD], w2=wp[(k+2)*DD], w3=wp[(k+3)*DD];
      #pragma unroll
      for (int t=0;t<TPB;++t){
        float4 c4 = *(const float4*)&cat[t][k];
        y[t]=fmaf(c4.x,w0,y[t]); y[t]=fmaf(c4.y,w1,y[t]);
        y[t]=fmaf(c4.z,w2,y[t]); y[t]=fmaf(c4.w,w3,y[t]);
      }
    }
  }
  #pragma unroll
  for (int t=0;t<TPB;++t) pA[part][t][d] = y[t];
  __syncthreads();

  // ---- combine + bias + residual + LN -> h1s (token t = part) ----
  {
    int t = part;
    float v = pA[0][t][d]+pA[1][t][d]+pA[2][t][d]+pA[3][t][d] + bp[d] + cat[t][d];
    float s=v,q=v*v; waveRed2(s,q);
    if (lane==0){ red[t][wid][0]=s; red[t][wid][1]=q; }
    __syncthreads();
    float S=red[t][0][0]+red[t][1][0], Q=red[t][0][1]+red[t][1][1];
    float m=S*(1.f/DD), var=Q*(1.f/DD)-m*m, rs=rsqrtf(var+EPSV);
    h1s[t][d] = (v-m)*rs*gp[d] + bgp[d];
  }
  __syncthreads();

  // ---- stage B: u = relu(h1 @ W1 + b1); thread = column j ----
  {
    int j = tid;
    float acc[TPB];
    float b1v = b1[j];
    #pragma unroll
    for (int t=0;t<TPB;++t) acc[t]=b1v;
    const float* w1p = W1 + j;
    for (int k=0;k<DD;k+=4){
      float w0=w1p[(k+0)*HH], w1=w1p[(k+1)*HH], w2=w1p[(k+2)*HH], w3=w1p[(k+3)*HH];
      #pragma unroll
      for (int t=0;t<TPB;++t){
        float4 h4 = *(const float4*)&h1s[t][k];
        acc[t]=fmaf(h4.x,w0,acc[t]); acc[t]=fmaf(h4.y,w1,acc[t]);
        acc[t]=fmaf(h4.z,w2,acc[t]); acc[t]=fmaf(h4.w,w3,acc[t]);
      }
    }
    #pragma unroll
    for (int t=0;t<TPB;++t) us[t][j]=fmaxf(acc[t],0.f);
  }
  __syncthreads();

  // ---- stage C: partial z over j in [part*128, part*128+128) ----
  float z[TPB];
  #pragma unroll
  for (int t=0;t<TPB;++t) z[t]=0.f;
  {
    const float* w2p = W2 + d;
    int j0 = part*128;
    for (int j=j0;j<j0+128;j+=4){
      float w0=w2p[(j+0)*DD], w1=w2p[(j+1)*DD], w2v=w2p[(j+2)*DD], w3=w2p[(j+3)*DD];
      #pragma unroll
      for (int t=0;t<TPB;++t){
        float4 u4 = *(const float4*)&us[t][j];
        z[t]=fmaf(u4.x,w0,z[t]); z[t]=fmaf(u4.y,w1,z[t]);
        z[t]=fmaf(u4.z,w2v,z[t]); z[t]=fmaf(u4.w,w3,z[t]);
      }
    }
  }
  #pragma unroll
  for (int t=0;t<TPB;++t) pA[part][t][d]=z[t];   // pA reads long done
  __syncthreads();

  // ---- combine + bias + residual + LN -> h (in place) + pool partial ----
  {
    int t = part;
    float v = pA[0][t][d]+pA[1][t][d]+pA[2][t][d]+pA[3][t][d] + b2[d] + h1s[t][d];
    float s=v,q=v*v; waveRed2(s,q);
    if (lane==0){ red[t][wid][0]=s; red[t][wid][1]=q; }
    __syncthreads();
    float S=red[t][0][0]+red[t][1][0], Q=red[t][0][1]+red[t][1][1];
    float m=S*(1.f/DD), var=Q*(1.f/DD)-m*m, rs=rsqrtf(var+EPSV);
    float hv = (v-m)*rs*gf[d] + bgf[d];
    h[(size_t)(t0+t)*DD + d] = hv;
    cat[t][d] = hv;                       // reuse cat as final-h buffer
  }
  if (write_pool){
    __syncthreads();
    if (part==0){
      int n0 = t0 & 255;
      float m1 = cat[0][d], m2=-3.4e38f; int am=n0;
      #pragma unroll
      for (int p=1;p<TPB;++p) poolMerge(m1,m2,am, cat[p][d], -3.4e38f, n0+p);
      int blk = (t0>>2)&(BPB-1);
      size_t idx = ((size_t)b*BPB+blk)*DD + d;
      qm1p[idx]=m1; qm2p[idx]=m2; qargp[idx]=am;
    }
  }
}

extern "C" void kernel_launch(void* const* d_in, const int* in_sizes, int n_in,
                              void* d_out, int out_size, void* d_ws, size_t ws_size,
                              hipStream_t stream)
{
  const float* x   = (const float*)d_in[0];
  const float* We  = (const float*)d_in[1];
  const float* be  = (const float*)d_in[2];
  const float* ge  = (const float*)d_in[3];
  const float* bge = (const float*)d_in[4];
  const float* Wp  = (const float*)d_in[5];
  const float* bp  = (const float*)d_in[6];
  const float* gp  = (const float*)d_in[7];
  const float* bgp = (const float*)d_in[8];
  const float* W1  = (const float*)d_in[9];
  const float* b1  = (const float*)d_in[10];
  const float* W2  = (const float*)d_in[11];
  const float* b2  = (const float*)d_in[12];
  const float* gf  = (const float*)d_in[13];
  const float* bgf = (const float*)d_in[14];

  // h lives in d_out; final layer's in-place update IS the output.
  float* h = (float*)d_out;
  const size_t NSTAT = (size_t)BB*BPB*DD;      // 64K entries
  float* pA1 = (float*)d_ws;
  float* pA2 = pA1 + NSTAT;
  int*   pAa = (int*)(pA2 + NSTAT);
  float* pB1 = (float*)(pAa + NSTAT);
  float* pB2 = pB1 + NSTAT;
  int*   pBa = (int*)(pB2 + NSTAT);

  const int grid = (BB*NN)/TPB;   // 512

  k_embed<<<grid, 512, 0, stream>>>(x, We, be, ge, bge, h, pA1, pA2, pAa);

  k_layer<<<grid, 512, 0, stream>>>(h, pA1, pA2, pAa, pB1, pB2, pBa, 1,
      Wp,                bp,        gp,        bgp,
      W1,                b1,        W2,        b2,
      gf,                bgf);

  k_layer<<<grid, 512, 0, stream>>>(h, pB1, pB2, pBa, pB1, pB2, pBa, 0,
      Wp + (size_t)2*DD*DD, bp + DD,  gp + DD,  bgp + DD,
      W1 + (size_t)DD*HH,   b1 + HH,  W2 + (size_t)HH*DD, b2 + DD,
      gf + DD,              bgf + DD);
}